// Round 8
// baseline (224.484 us; speedup 1.0000x reference)
//
#include <hip/hip_runtime.h>
#include <hip/hip_fp16.h>

// ColorDeformConv2d — round 12: fatter staged iters + cross-barrier prefetch.
// vs r11 (spill-free, 4 blocks/CU, 143us): (1) 2-chunk staged iterations
// (8 MFMA/wave/iter), 9 barrier-iters per sweep (was 18). (2) T14 prefetch:
// loads for iter it+1 issued at it-1 -> a FULL iteration covers L2 latency
// (reg loads stay in flight across __syncthreads). (3) staging ring overlaid
// on the Amod region (time-disjoint within a pass): LDS 36.1K -> 27.3K.
// (4) w4h read as one uint2 LDS op. Same ks order -> bit-identical numerics.
//
// Reg model (r8-r11 measured): 512 regs/SIMD; 128/wave cap -> acc[2]+oa=48
// acc + ~80 arch, no spill.
//
// ws (u16 elems): A_c[20mt][36ks][64l][8] @0 (368640), A_pm @368640 (18432),
// A_conv[2][40][64][8] @387072 (40960), Wcd row-major @428032 (8192),
// fused2 @436224 (4*64*16384, cg-interleaved). Total 9.3 MB.
//
// k3 LDS (27904 B, 4 blocks/CU): R@0 16K (staging ring 2x8K during k-loops;
// Amod 16K during scatter/out-GEMM; uL 6.9K in pm->tables window) |
// sidx@16384 2304 | w4h@18688 4608 | mL@23296 2304 | bcL@25600 2304

typedef __attribute__((ext_vector_type(8))) __bf16 bf16x8;
typedef __attribute__((ext_vector_type(16))) float f32x16;
#define MFMA32(a, b, c) __builtin_amdgcn_mfma_f32_32x32x16_bf16((a), (b), (c), 0, 0, 0)

#define WS_AC    0
#define WS_APM   368640
#define WS_ACONV 387072
#define WS_WCD   428032
#define WS_F2    436224

struct f2pair { float x, y; };              // align 4: legal 4B-aligned dwordx2

__device__ __forceinline__ unsigned short f2bf(float f) {
    unsigned u = __float_as_uint(f);
    return (unsigned short)((u + 0x7FFFu + ((u >> 16) & 1u)) >> 16);   // RNE
}
__device__ __forceinline__ float fast_rcp(float x) {
#if __has_builtin(__builtin_amdgcn_rcpf)
    return __builtin_amdgcn_rcpf(x);
#else
    return 1.0f / x;
#endif
}
__device__ __forceinline__ float fast_tanh(float x) {
    float t = __expf(2.0f * x);
    return 1.0f - 2.0f * fast_rcp(t + 1.0f);
}
__device__ __forceinline__ float fast_sigmoid(float x) {
    return fast_rcp(1.0f + __expf(-x));
}

// ---------------- prep: weight repack to frag-order bf16 (unchanged) --------
__global__ void prep_kernel(const float* __restrict__ w_c, const float* __restrict__ w_p,
                            const float* __restrict__ w_m, const float* __restrict__ w_conv,
                            const float* __restrict__ w_cd, unsigned short* __restrict__ ws) {
    int i = blockIdx.x * 256 + threadIdx.x;
    if (i >= 436224) return;
    float val;
    if (i < WS_APM) {                       // A_c: row=gmt*32+(l&31), k'=ks*16+(l>>5)*8+j
        int t = i, j = t & 7, l = (t >> 3) & 63, r = t >> 9, ks = r % 36, gmt = r / 36;
        int row = gmt * 32 + (l & 31);
        int kp = ks * 16 + (l >> 5) * 8 + j, tap = kp >> 6, ci = kp & 63;
        val = (row < 576) ? w_c[row * 576 + ci * 9 + tap] : 0.0f;
    } else if (i < WS_ACONV) {              // A_pm: rows 0-17 w_p, 18-26 w_m
        int t = i - WS_APM, j = t & 7, l = (t >> 3) & 63, ks = t >> 9;
        int row = l & 31;
        int kp = ks * 16 + (l >> 5) * 8 + j, tap = kp >> 6, ci = kp & 63;
        val = (row < 18) ? w_p[row * 576 + ci * 9 + tap]
            : (row < 27) ? w_m[(row - 18) * 576 + ci * 9 + tap] : 0.0f;
    } else if (i < WS_WCD) {                // A_conv: k = U-row (natural order)
        int t = i - WS_ACONV, j = t & 7, l = (t >> 3) & 63, r = t >> 9;
        int gks = r % 40, ocT = r / 40;
        int oc = ocT * 32 + (l & 31);
        int krow = gks * 16 + (l >> 5) * 8 + j;
        val = (krow < 576) ? w_conv[oc * 576 + krow] : 0.0f;
    } else {                                // Wcd row-major [64][128]
        val = w_cd[i - WS_WCD];
    }
    ws[i] = f2bf(val);
}

// ------ im2col B-stage (64-px, single 32-k' chunk): global->reg, reg->LDS ----
__device__ __forceinline__ uint4 stage_load64(const unsigned short* f2b, int h,
                                              int px0, int chunk, int tid) {
    int tap = chunk >> 1;
    int dh = tap / 3 - 1, dw = tap % 3 - 1;
    int hs = h + dh;
    int kg = tid >> 6, px = tid & 63;       // 256 tasks: kg(4) x px(64)
    int cg = (chunk & 1) * 4 + kg;          // channels cg*8 .. cg*8+7
    int wsrc = px0 + px + dw;
    uint4 pk = {0u, 0u, 0u, 0u};
    if (((unsigned)hs < 128u) && ((unsigned)wsrc < 128u))
        pk = *(const uint4*)(f2b + (((size_t)cg << 14) + (hs << 7) + wsrc) * 8);
    return pk;
}
__device__ __forceinline__ void stage_write64(char* Bst, uint4 pk, int tid) {
    int kg = tid >> 6, px = tid & 63;
    *(uint4*)(Bst + ((kg >> 1) * 2 + (px >> 5)) * 1024
                  + ((px & 31) + 32 * (kg & 1)) * 16) = pk;
}

// ---------------- k2: fused 1x1 conv -> fused2 cg-interleaved (unchanged) ----
__global__ __launch_bounds__(256, 4)
void k2_fused(const float* __restrict__ x, const float* __restrict__ ref,
              const float* __restrict__ b_cd, const unsigned short* __restrict__ wsbf,
              unsigned short* __restrict__ ws) {
    __shared__ __align__(16) char B0[32768];
    const int tid = threadIdx.x, l = tid & 63, w = tid >> 6;
    const int b = blockIdx.y, p0 = blockIdx.x * 128;
    const int rl31 = l & 31, kh8 = (l >> 5) * 8;

    #pragma unroll
    for (int it = 0; it < 8; ++it) {        // 2048 tasks: kg(16) x px(128)
        int task = it * 256 + tid;
        int kg = task >> 7, px = task & 127;
        const float* src = (kg < 8) ? x : ref;
        int kbase = (kg & 7) * 8;
        unsigned short v[8];
        #pragma unroll
        for (int j = 0; j < 8; ++j)
            v[j] = f2bf(src[(((size_t)b * 64 + kbase + j) << 14) + p0 + px]);
        uint4 pk;
        pk.x = (unsigned)v[0] | ((unsigned)v[1] << 16);
        pk.y = (unsigned)v[2] | ((unsigned)v[3] << 16);
        pk.z = (unsigned)v[4] | ((unsigned)v[5] << 16);
        pk.w = (unsigned)v[6] | ((unsigned)v[7] << 16);
        *(uint4*)(B0 + ((kg >> 1) * 4 + (px >> 5)) * 1024
                      + ((px & 31) + 32 * (kg & 1)) * 16) = pk;
    }
    __syncthreads();

    f32x16 a0, a1;
    #pragma unroll
    for (int r = 0; r < 16; ++r) { a0[r] = 0.0f; a1[r] = 0.0f; }
    const unsigned short* A0 = wsbf + WS_WCD + rl31 * 128 + kh8;
    #pragma unroll
    for (int s = 0; s < 8; ++s) {
        bf16x8 bf = *(bf16x8*)(B0 + ((s * 4 + w) * 64 + l) * 16);
        bf16x8 x0 = *(const bf16x8*)(A0 + s * 16);
        bf16x8 x1 = *(const bf16x8*)(A0 + 32 * 128 + s * 16);
        a0 = MFMA32(x0, bf, a0);
        a1 = MFMA32(x1, bf, a1);
    }
    unsigned short* f2 = ws + WS_F2 + ((size_t)b << 20);
    int px = p0 + w * 32 + rl31;
    int h4 = (l >> 5) * 4;
    #pragma unroll
    for (int t = 0; t < 2; ++t)
        #pragma unroll
        for (int q = 0; q < 4; ++q) {
            ushort4 st;
            float v0 = (t ? a1[q * 4 + 0] : a0[q * 4 + 0]) + b_cd[t * 32 + 8 * q + h4 + 0];
            float v1 = (t ? a1[q * 4 + 1] : a0[q * 4 + 1]) + b_cd[t * 32 + 8 * q + h4 + 1];
            float v2 = (t ? a1[q * 4 + 2] : a0[q * 4 + 2]) + b_cd[t * 32 + 8 * q + h4 + 2];
            float v3 = (t ? a1[q * 4 + 3] : a0[q * 4 + 3]) + b_cd[t * 32 + 8 * q + h4 + 3];
            st.x = f2bf(v0); st.y = f2bf(v1); st.z = f2bf(v2); st.w = f2bf(v3);
            *(ushort4*)(f2 + ((size_t)((t * 4 + q) << 14) + px) * 8 + h4) = st;
        }
}

// ---------------- k3: 2-chunk iters, cross-barrier prefetch, shared LDS -----
__global__ __launch_bounds__(256, 4)
void k3_main(const float* __restrict__ x, const float* __restrict__ b_c,
             const float* __restrict__ b_p, const float* __restrict__ b_m,
             const unsigned short* __restrict__ wsbf, float* __restrict__ out) {
    __shared__ __align__(16) char lds[27904];
    char* R = lds;                          // 16K: staging ring / Amod / uL
    float* uL = (float*)lds;                // 6912B, live pm-end..tables-end
    short* sidx = (short*)(lds + 16384);
    unsigned short* w4h = (unsigned short*)(lds + 18688);
    float* mL = (float*)(lds + 23296);
    float* bcL = (float*)(lds + 25600);

    const int tid = threadIdx.x, l = tid & 63, w = tid >> 6;   // 4 waves
    // XCD-banded decode: xcd = id&7 owns h band [xcd*16, xcd*16+16) x b x half
    const int id = blockIdx.x;
    const int hbLin = (id & 7) * 128 + (id >> 3);
    const int half = hbLin & 1, b = (hbLin >> 1) & 3, h = hbLin >> 3;
    const int px0 = half * 64;
    const unsigned short* f2b = wsbf + WS_F2 + ((size_t)b << 20);

    for (int i = tid; i < 576; i += 256) bcL[i] = b_c[i];

    // ================= pm pre-phase: U_pm[27][64], 9 pair-iters =============
    {
        f32x16 pm;
        #pragma unroll
        for (int r = 0; r < 16; ++r) pm[r] = 0.0f;
        uint4 a0 = stage_load64(f2b, h, px0, 0, tid);
        uint4 a1 = stage_load64(f2b, h, px0, 1, tid);
        stage_write64(R, a0, tid);
        stage_write64(R + 4096, a1, tid);
        uint4 b0 = stage_load64(f2b, h, px0, 2, tid);
        uint4 b1 = stage_load64(f2b, h, px0, 3, tid);
        __syncthreads();
        #pragma unroll 1
        for (int it = 0; it < 9; ++it) {
            char* cur = R + (it & 1) * 8192;
            char* nxt = R + ((it + 1) & 1) * 8192;
            uint4 c0 = b0, c1 = b1;
            if (it < 7) {
                c0 = stage_load64(f2b, h, px0, 2 * it + 4, tid);
                c1 = stage_load64(f2b, h, px0, 2 * it + 5, tid);
            }
            if (w < 2) {                    // wave w owns n-tile nt=w
                #pragma unroll
                for (int q = 0; q < 4; ++q) {
                    int ks = it * 4 + q;
                    bf16x8 bf = *(bf16x8*)(cur + (q >> 1) * 4096
                                               + (((q & 1) * 2 + w) * 64 + l) * 16);
                    bf16x8 apm = *(const bf16x8*)(wsbf + WS_APM + ((ks * 64 + l) << 3));
                    pm = MFMA32(apm, bf, pm);
                }
            }
            if (it < 8) {
                stage_write64(nxt, b0, tid);
                stage_write64(nxt + 4096, b1, tid);
            }
            __syncthreads();
            b0 = c0; b1 = c1;
        }
        if (w < 2) {                        // pm -> uL (f32), nt = w
            int pxp = w * 32 + (l & 31);
            #pragma unroll
            for (int reg = 0; reg < 16; ++reg) {
                int rl = (reg & 3) + 8 * (reg >> 2) + 4 * (l >> 5);
                uL[rl * 64 + pxp] = pm[reg];
            }
        }
        __syncthreads();
    }

    // ============ tables from uL: pair-based bilinear (once per block) =======
    #pragma unroll 1
    for (int i = tid; i < 576; i += 256) {
        int n = i >> 6, px = i & 63;
        float offr = uL[n * 64 + px] + b_p[n];
        float offc = uL[(9 + n) * 64 + px] + b_p[9 + n];
        float mraw = uL[(18 + n) * 64 + px] + b_m[n];
        int nr = n / 3, nc = n - nr * 3;
        float pr = (float)(h + nr) + offr;
        float pc = (float)(px0 + px + nc) + offc;
        float flr = floorf(pr), flc = floorf(pc);
        float prc = fminf(fmaxf(pr, 0.0f), 129.0f);
        float pcc = fminf(fmaxf(pc, 0.0f), 129.0f);
        // rows
        float q0r = fminf(fmaxf(flr, 0.0f), 129.0f);
        float q1r = fminf(fmaxf(flr + 1.0f, 0.0f), 129.0f);
        int ir0 = (int)q0r, ir1 = (int)q1r;
        bool vr0 = (ir0 >= 1) && (ir0 <= 128), vr1 = (ir1 >= 1) && (ir1 <= 128);
        float wr0 = vr0 ? (1.0f + q0r - prc) : 0.0f;
        float wr1 = vr1 ? (1.0f - (q1r - prc)) : 0.0f;
        // cols
        float q0c = fminf(fmaxf(flc, 0.0f), 129.0f);
        float q1c = fminf(fmaxf(flc + 1.0f, 0.0f), 129.0f);
        int ic0 = (int)q0c, ic1 = (int)q1c;
        bool vc0 = (ic0 >= 1) && (ic0 <= 128), vc1 = (ic1 >= 1) && (ic1 <= 128);
        float wc0 = vc0 ? (1.0f + q0c - pcc) : 0.0f;
        float wc1 = vc1 ? (1.0f - (q1c - pcc)) : 0.0f;
        // pair base in x-coords; fold clamp-remap + validity into slot weights
        int cx0 = ic0 - 1, cx1 = ic1 - 1;
        int base = min(max(cx0, 0), 126);
        float ws0 = ((base == cx0) && vc0 ? wc0 : 0.0f)
                  + ((base == cx1) && vc1 ? wc1 : 0.0f);
        float ws1 = ((base + 1 == cx0) && vc0 ? wc0 : 0.0f)
                  + ((base + 1 == cx1) && vc1 ? wc1 : 0.0f);
        int rx0 = min(max(ir0 - 1, 0), 127), rx1 = min(max(ir1 - 1, 0), 127);
        short2 s2;
        s2.x = (short)(rx0 * 128 + base);
        s2.y = (short)(rx1 * 128 + base);
        ((short2*)sidx)[px * 9 + n] = s2;
        int wb = (px * 9 + n) * 4;
        w4h[wb + 0] = __half_as_ushort(__float2half(wr0 * ws0));
        w4h[wb + 1] = __half_as_ushort(__float2half(wr0 * ws1));
        w4h[wb + 2] = __half_as_ushort(__float2half(wr1 * ws0));
        w4h[wb + 3] = __half_as_ushort(__float2half(wr1 * ws1));
        mL[n * 64 + px] = fast_sigmoid(mraw);
    }

    // ================= 5 thin m-passes (1 m-tile/wave each) =================
    f32x16 oa;
    #pragma unroll
    for (int r = 0; r < 16; ++r) oa[r] = 0.0f;
    const float* xb = x + (((size_t)b * 64) << 14);
    const int ocT = w >> 1, nT2 = w & 1;

    #pragma unroll 1
    for (int p = 0; p < 5; ++p) {
        const int mt = p * 4 + w;           // exact 20 m-tiles over 5x4 waves
        f32x16 acc[2];                      // [nt], statically indexed
        #pragma unroll
        for (int j = 0; j < 2; ++j)
            #pragma unroll
            for (int r = 0; r < 16; ++r) acc[j][r] = 0.0f;

        // issue chunk 0..3 loads early (hide under the pass-start barrier)
        uint4 a0 = stage_load64(f2b, h, px0, 0, tid);
        uint4 a1 = stage_load64(f2b, h, px0, 1, tid);
        uint4 b0 = stage_load64(f2b, h, px0, 2, tid);
        uint4 b1 = stage_load64(f2b, h, px0, 3, tid);
        __syncthreads();                    // R free: tables / prev out-GEMM done
        stage_write64(R, a0, tid);
        stage_write64(R + 4096, a1, tid);
        __syncthreads();

        // ---- U-GEMM k-loop: 9 pair-iters, 8 MFMA/wave/iter, T14 prefetch ----
        #pragma unroll 1
        for (int it = 0; it < 9; ++it) {
            char* cur = R + (it & 1) * 8192;
            char* nxt = R + ((it + 1) & 1) * 8192;
            uint4 c0 = b0, c1 = b1;
            if (it < 7) {
                c0 = stage_load64(f2b, h, px0, 2 * it + 4, tid);
                c1 = stage_load64(f2b, h, px0, 2 * it + 5, tid);
            }
            #pragma unroll
            for (int q = 0; q < 4; ++q) {
                const int ks = it * 4 + q;
                char* fb = cur + (q >> 1) * 4096;
                bf16x8 bf0 = *(bf16x8*)(fb + (((q & 1) * 2 + 0) * 64 + l) * 16);
                bf16x8 bf1 = *(bf16x8*)(fb + (((q & 1) * 2 + 1) * 64 + l) * 16);
                bf16x8 af = *(const bf16x8*)(wsbf + WS_AC
                                + (((mt * 36 + ks) * 64 + l) << 3));
                acc[0] = MFMA32(af, bf0, acc[0]);
                acc[1] = MFMA32(af, bf1, acc[1]);
            }
            if (it < 8) {
                stage_write64(nxt, b0, tid);
                stage_write64(nxt + 4096, b1, tid);
            }
            __syncthreads();
            b0 = c0; b1 = c1;
        }

        // ---- epilogue: tanh + pair-load bilinear + modulate (in regs) ----
        const int rowbase = mt * 32;
        #pragma unroll
        for (int j = 0; j < 2; ++j) {
            const int pxe = j * 32 + (l & 31);
            if (rowbase < 576) {
                #pragma unroll
                for (int reg = 0; reg < 16; ++reg) {
                    int rl = (reg & 3) + 8 * (reg >> 2) + 4 * (l >> 5);
                    int row = rowbase + rl;
                    int c = row / 9, n = row - c * 9;
                    float uv = acc[j][reg] + bcL[row];
                    float t = fast_tanh(uv);
                    short2 s2 = ((short2*)sidx)[pxe * 9 + n];
                    int wb = (pxe * 9 + n) * 4;
                    uint2 wv = *(const uint2*)(w4h + wb);       // one b64 LDS read
                    float w0 = __half2float(__ushort_as_half((unsigned short)(wv.x & 0xffffu)));
                    float w1 = __half2float(__ushort_as_half((unsigned short)(wv.x >> 16)));
                    float w2 = __half2float(__ushort_as_half((unsigned short)(wv.y & 0xffffu)));
                    float w3 = __half2float(__ushort_as_half((unsigned short)(wv.y >> 16)));
                    const float* xp = xb + ((size_t)c << 14);
                    f2pair v0 = *(const f2pair*)(xp + s2.x);
                    f2pair v1 = *(const f2pair*)(xp + s2.y);
                    float samp = w0 * v0.x + w1 * v0.y + w2 * v1.x + w3 * v1.y;
                    acc[j][reg] = mL[n * 64 + pxe] * (samp + t);
                    // bound gather clustering: <=8 loads in flight
                    if ((reg & 3) == 3) __builtin_amdgcn_sched_barrier(0);
                }
            } else {
                #pragma unroll
                for (int reg = 0; reg < 16; ++reg) acc[j][reg] = 0.0f;
            }
        }

        // ---- scatter 128 rows -> Amod (=R), then out-GEMM accumulate ----
        // (k-loop's final barrier already separates last Bst reads from these
        //  writes; scatter lanes write disjoint bytes)
        #pragma unroll
        for (int j = 0; j < 2; ++j) {
            #pragma unroll
            for (int reg = 0; reg < 16; ++reg) {
                int rl = (reg & 3) + 8 * (reg >> 2) + 4 * (l >> 5);
                int k = w * 32 + rl;        // pass-local row in [0,128)
                *(unsigned short*)(R + ((k >> 4) * 2 + j) * 1024
                        + ((l & 31) + 32 * ((k >> 3) & 1)) * 16 + (k & 7) * 2)
                    = f2bf(acc[j][reg]);
            }
        }
        __syncthreads();
        #pragma unroll
        for (int ks8 = 0; ks8 < 8; ++ks8) {
            bf16x8 af = *(const bf16x8*)(wsbf + WS_ACONV
                            + (((ocT * 40 + p * 8 + ks8) * 64 + l) << 3));
            bf16x8 bf = *(bf16x8*)(R + (ks8 * 2 + nT2) * 1024 + l * 16);
            oa = MFMA32(af, bf, oa);
        }
    }

    // ---- final store: each out element written exactly once ----
    float* ob = out + (((size_t)b * 64) << 14) + (h << 7) + px0 + nT2 * 32 + (l & 31);
    #pragma unroll
    for (int reg = 0; reg < 16; ++reg) {
        int rl = (reg & 3) + 8 * (reg >> 2) + 4 * (l >> 5);
        int oc = ocT * 32 + rl;
        ob[(size_t)oc << 14] = oa[reg];
    }
}

extern "C" void kernel_launch(void* const* d_in, const int* in_sizes, int n_in,
                              void* d_out, int out_size, void* d_ws, size_t ws_size,
                              hipStream_t stream) {
    const float* x      = (const float*)d_in[0];
    const float* ref    = (const float*)d_in[1];
    const float* w_cd   = (const float*)d_in[2];
    const float* b_cd   = (const float*)d_in[3];
    const float* w_p    = (const float*)d_in[4];
    const float* b_p    = (const float*)d_in[5];
    const float* w_m    = (const float*)d_in[6];
    const float* b_m    = (const float*)d_in[7];
    const float* w_c    = (const float*)d_in[8];
    const float* b_c    = (const float*)d_in[9];
    const float* w_conv = (const float*)d_in[10];
    float* out = (float*)d_out;
    unsigned short* wsbf = (unsigned short*)d_ws;

    hipLaunchKernelGGL(prep_kernel, dim3(1704), dim3(256), 0, stream,
                       w_c, w_p, w_m, w_conv, w_cd, wsbf);
    hipLaunchKernelGGL(k2_fused, dim3(128, 4), dim3(256), 0, stream,
                       x, ref, b_cd, wsbf, wsbf);
    hipLaunchKernelGGL(k3_main, dim3(1024), dim3(256), 0, stream,
                       x, b_c, b_p, b_m, wsbf, out);
}